// Round 1
// baseline (1257.985 us; speedup 1.0000x reference)
//
#include <hip/hip_runtime.h>
#include <math.h>

#define NEG_SLOPE 0.2f

__device__ __forceinline__ float lrelu(float x) { return x > 0.f ? x : NEG_SLOPE * x; }

// monotonic float->uint mapping for atomicMax (order-preserving for all finite floats)
__device__ __forceinline__ unsigned encf(float f) {
  unsigned s = __float_as_uint(f);
  return (s & 0x80000000u) ? ~s : (s | 0x80000000u);
}
__device__ __forceinline__ float decf(unsigned u) {
  return __uint_as_float((u & 0x80000000u) ? (u ^ 0x80000000u) : ~u);
}

// ---------------- Kernel A: h1 = x @ W1 (fp32, LDS-tiled), fused per-head attention dots
// block 256 threads, 32 nodes/block. W1 (64KB) + x tile (16KB) in LDS.
// thread t: cols (t%32)*4..+3, nodes n0+(t/32)*4..+3  -> 16 fp32 acc regs
__global__ __launch_bounds__(256) void k_gemm1_att(
    const float* __restrict__ x, const float* __restrict__ W1,
    const float* __restrict__ att_src, const float* __restrict__ att_dst,
    float* __restrict__ h1, float* __restrict__ as1, float* __restrict__ ad1,
    int N)
{
  __shared__ float Wls[128 * 128];
  __shared__ float xls[32][128];
  const int tid = threadIdx.x;
  const float4* __restrict__ W4 = (const float4*)W1;
  float4* Wls4 = (float4*)Wls;
#pragma unroll
  for (int i = 0; i < 16; ++i) Wls4[tid + i * 256] = W4[tid + i * 256];

  const int cg = tid & 31;      // col group (float4 index)
  const int col = cg << 2;
  const int ng = tid >> 5;      // node group 0..7
  const int nb = ng << 2;       // first node row in x tile
  const int n0 = blockIdx.x * 32;

  const float4 avs = *(const float4*)(att_src + col);
  const float4 avd = *(const float4*)(att_dst + col);

  const float4* __restrict__ x4 = (const float4*)x;
  float4* xls4 = (float4*)xls;
#pragma unroll
  for (int i = 0; i < 4; ++i) {
    int idx = tid + i * 256;
    int r = idx >> 5, c = idx & 31;
    int n = n0 + r; if (n >= N) n = N - 1;
    xls4[idx] = x4[(size_t)n * 32 + c];
  }
  __syncthreads();

  float4 a0 = {0,0,0,0}, a1 = {0,0,0,0}, a2 = {0,0,0,0}, a3 = {0,0,0,0};
#pragma unroll 8
  for (int k = 0; k < 128; ++k) {
    float4 w = Wls4[(k << 5) + cg];
    float x0 = xls[nb + 0][k];
    float x1 = xls[nb + 1][k];
    float x2 = xls[nb + 2][k];
    float x3 = xls[nb + 3][k];
    a0.x = fmaf(x0, w.x, a0.x); a0.y = fmaf(x0, w.y, a0.y); a0.z = fmaf(x0, w.z, a0.z); a0.w = fmaf(x0, w.w, a0.w);
    a1.x = fmaf(x1, w.x, a1.x); a1.y = fmaf(x1, w.y, a1.y); a1.z = fmaf(x1, w.z, a1.z); a1.w = fmaf(x1, w.w, a1.w);
    a2.x = fmaf(x2, w.x, a2.x); a2.y = fmaf(x2, w.y, a2.y); a2.z = fmaf(x2, w.z, a2.z); a2.w = fmaf(x2, w.w, a2.w);
    a3.x = fmaf(x3, w.x, a3.x); a3.y = fmaf(x3, w.y, a3.y); a3.z = fmaf(x3, w.z, a3.z); a3.w = fmaf(x3, w.w, a3.w);
  }

#define OUTJ(j, acc) { \
    int n = n0 + nb + j; \
    if (n < N) *(float4*)(h1 + (size_t)n * 128 + col) = acc; \
    float psv = acc.x*avs.x + acc.y*avs.y + acc.z*avs.z + acc.w*avs.w; \
    float pdv = acc.x*avd.x + acc.y*avd.y + acc.z*avd.z + acc.w*avd.w; \
    psv += __shfl_xor(psv, 1); psv += __shfl_xor(psv, 2); \
    pdv += __shfl_xor(pdv, 1); pdv += __shfl_xor(pdv, 2); \
    if ((tid & 3) == 0 && n < N) { as1[(size_t)n * 8 + (cg >> 2)] = psv; ad1[(size_t)n * 8 + (cg >> 2)] = pdv; } \
  }
  OUTJ(0, a0) OUTJ(1, a1) OUTJ(2, a2) OUTJ(3, a3)
#undef OUTJ
}

// ---------------- Kernel B: per-edge, per-head leaky_relu(a_src[s]+a_dst[d]) -> atomicMax into m1
__global__ __launch_bounds__(256) void k_edge1_max(
    const int* __restrict__ ei, int E, int N,
    const float* __restrict__ as1, const float* __restrict__ ad1,
    unsigned* __restrict__ m1u)
{
  int e = blockIdx.x * 256 + threadIdx.x;
  if (e >= E + N) return;
  int s, d;
  if (e < E) { s = ei[e]; d = ei[E + e]; } else { s = d = e - E; }
  const float4 sa = *(const float4*)(as1 + (size_t)s * 8);
  const float4 sb = *(const float4*)(as1 + (size_t)s * 8 + 4);
  const float4 da = *(const float4*)(ad1 + (size_t)d * 8);
  const float4 db = *(const float4*)(ad1 + (size_t)d * 8 + 4);
  float v[8] = { sa.x+da.x, sa.y+da.y, sa.z+da.z, sa.w+da.w,
                 sb.x+db.x, sb.y+db.y, sb.z+db.z, sb.w+db.w };
  unsigned* md = m1u + (size_t)d * 8;
#pragma unroll
  for (int h = 0; h < 8; ++h) atomicMax(&md[h], encf(lrelu(v[h])));
}

// ---------------- Kernel C: exp(e - m[dst]) -> atomicAdd into s1
__global__ __launch_bounds__(256) void k_edge1_sum(
    const int* __restrict__ ei, int E, int N,
    const float* __restrict__ as1, const float* __restrict__ ad1,
    const unsigned* __restrict__ m1u, float* __restrict__ s1)
{
  int e = blockIdx.x * 256 + threadIdx.x;
  if (e >= E + N) return;
  int s, d;
  if (e < E) { s = ei[e]; d = ei[E + e]; } else { s = d = e - E; }
  const float4 sa = *(const float4*)(as1 + (size_t)s * 8);
  const float4 sb = *(const float4*)(as1 + (size_t)s * 8 + 4);
  const float4 da = *(const float4*)(ad1 + (size_t)d * 8);
  const float4 db = *(const float4*)(ad1 + (size_t)d * 8 + 4);
  float v[8] = { sa.x+da.x, sa.y+da.y, sa.z+da.z, sa.w+da.w,
                 sb.x+db.x, sb.y+db.y, sb.z+db.z, sb.w+db.w };
#pragma unroll
  for (int h = 0; h < 8; ++h) {
    float ex = expf(lrelu(v[h]) - decf(m1u[(size_t)d * 8 + h]));
    unsafeAtomicAdd(&s1[(size_t)d * 8 + h], ex);
  }
}

// ---------------- Kernel D: aggregation y1[dst] += alpha * h1[src]; one wave per edge
__global__ __launch_bounds__(256) void k_agg1(
    const int* __restrict__ ei, int E, int N,
    const float* __restrict__ as1, const float* __restrict__ ad1,
    const unsigned* __restrict__ m1u, const float* __restrict__ s1,
    const float* __restrict__ h1, float* __restrict__ y1)
{
  const int lane = threadIdx.x & 63;
  const int e = blockIdx.x * 4 + (threadIdx.x >> 6);
  if (e >= E + N) return;
  int s, d;
  if (e < E) { s = ei[e]; d = ei[E + e]; } else { s = d = e - E; }
  const int ha = lane >> 4, hb = ha + 4;
  float va = lrelu(as1[(size_t)s*8 + ha] + ad1[(size_t)d*8 + ha]);
  float vb = lrelu(as1[(size_t)s*8 + hb] + ad1[(size_t)d*8 + hb]);
  float aa = expf(va - decf(m1u[(size_t)d*8 + ha])) / (s1[(size_t)d*8 + ha] + 1e-16f);
  float ab = expf(vb - decf(m1u[(size_t)d*8 + hb])) / (s1[(size_t)d*8 + hb] + 1e-16f);
  unsafeAtomicAdd(&y1[(size_t)d*128 + lane],      aa * h1[(size_t)s*128 + lane]);
  unsafeAtomicAdd(&y1[(size_t)d*128 + 64 + lane], ab * h1[(size_t)s*128 + 64 + lane]);
}

// ---------------- Kernel E: elu(y1 + b1), h2 = .@W2, attention dots for layer 2; one wave per node
__global__ __launch_bounds__(256) void k_l2prep(
    const float* __restrict__ y1, const float* __restrict__ b1,
    const float* __restrict__ W2, const float* __restrict__ ats2, const float* __restrict__ atd2,
    float* __restrict__ h2, float* __restrict__ as2, float* __restrict__ ad2, int N)
{
  const int lane = threadIdx.x & 63;
  const int n = blockIdx.x * 4 + (threadIdx.x >> 6);
  if (n >= N) return;
  float v0 = y1[(size_t)n*128 + lane] + b1[lane];
  float v1 = y1[(size_t)n*128 + 64 + lane] + b1[64 + lane];
  v0 = v0 > 0.f ? v0 : expm1f(v0);   // elu
  v1 = v1 > 0.f ? v1 : expm1f(v1);
  float2 w0 = ((const float2*)W2)[lane];
  float2 w1 = ((const float2*)W2)[lane + 64];
  float p0 = v0 * w0.x + v1 * w1.x;
  float p1 = v0 * w0.y + v1 * w1.y;
#pragma unroll
  for (int m = 1; m < 64; m <<= 1) { p0 += __shfl_xor(p0, m); p1 += __shfl_xor(p1, m); }
  if (lane == 0) {
    h2[(size_t)n*2] = p0; h2[(size_t)n*2+1] = p1;
    as2[n] = p0 * ats2[0] + p1 * ats2[1];
    ad2[n] = p0 * atd2[0] + p1 * atd2[1];
  }
}

// ---------------- Layer-2 edge kernels (1 head)
__global__ __launch_bounds__(256) void k_edge2_max(
    const int* __restrict__ ei, int E, int N,
    const float* __restrict__ as2, const float* __restrict__ ad2,
    unsigned* __restrict__ m2u)
{
  int e = blockIdx.x * 256 + threadIdx.x;
  if (e >= E + N) return;
  int s, d;
  if (e < E) { s = ei[e]; d = ei[E + e]; } else { s = d = e - E; }
  atomicMax(&m2u[d], encf(lrelu(as2[s] + ad2[d])));
}

__global__ __launch_bounds__(256) void k_edge2_sum(
    const int* __restrict__ ei, int E, int N,
    const float* __restrict__ as2, const float* __restrict__ ad2,
    const unsigned* __restrict__ m2u, float* __restrict__ s2)
{
  int e = blockIdx.x * 256 + threadIdx.x;
  if (e >= E + N) return;
  int s, d;
  if (e < E) { s = ei[e]; d = ei[E + e]; } else { s = d = e - E; }
  float ex = expf(lrelu(as2[s] + ad2[d]) - decf(m2u[d]));
  unsafeAtomicAdd(&s2[d], ex);
}

__global__ __launch_bounds__(256) void k_agg2(
    const int* __restrict__ ei, int E, int N,
    const float* __restrict__ as2, const float* __restrict__ ad2,
    const unsigned* __restrict__ m2u, const float* __restrict__ s2,
    const float* __restrict__ h2, float* __restrict__ out)
{
  int e = blockIdx.x * 256 + threadIdx.x;
  if (e >= E + N) return;
  int s, d;
  if (e < E) { s = ei[e]; d = ei[E + e]; } else { s = d = e - E; }
  float alpha = expf(lrelu(as2[s] + ad2[d]) - decf(m2u[d])) / (s2[d] + 1e-16f);
  unsafeAtomicAdd(&out[(size_t)d*2],     alpha * h2[(size_t)s*2]);
  unsafeAtomicAdd(&out[(size_t)d*2 + 1], alpha * h2[(size_t)s*2 + 1]);
}

__global__ __launch_bounds__(256) void k_bias2(float* __restrict__ out, const float* __restrict__ b2, int total) {
  int i = blockIdx.x * 256 + threadIdx.x;
  if (i < total) out[i] += b2[i & 1];
}

extern "C" void kernel_launch(void* const* d_in, const int* in_sizes, int n_in,
                              void* d_out, int out_size, void* d_ws, size_t ws_size,
                              hipStream_t stream) {
  const float* x    = (const float*)d_in[0];
  const int*   ei   = (const int*)d_in[1];
  const float* W1   = (const float*)d_in[2];
  const float* ats1 = (const float*)d_in[3];
  const float* atd1 = (const float*)d_in[4];
  const float* b1   = (const float*)d_in[5];
  const float* W2   = (const float*)d_in[6];
  const float* ats2 = (const float*)d_in[7];
  const float* atd2 = (const float*)d_in[8];
  const float* b2   = (const float*)d_in[9];
  float* out = (float*)d_out;

  const int N = in_sizes[0] / 128;
  const int E = in_sizes[1] / 2;
  const int E2 = E + N;

  // workspace layout (floats)
  float* ws = (float*)d_ws;
  size_t off = 0;
  float*    h1  = ws + off; off += (size_t)N * 128;
  float*    y1  = ws + off; off += (size_t)N * 128;
  float*    as1 = ws + off; off += (size_t)N * 8;
  float*    ad1 = ws + off; off += (size_t)N * 8;
  unsigned* m1u = (unsigned*)(ws + off); off += (size_t)N * 8;
  float*    s1  = ws + off; off += (size_t)N * 8;
  float*    h2  = ws + off; off += (size_t)N * 2;
  float*    as2 = ws + off; off += (size_t)N;
  float*    ad2 = ws + off; off += (size_t)N;
  unsigned* m2u = (unsigned*)(ws + off); off += (size_t)N;
  float*    s2  = ws + off; off += (size_t)N;

  // zero: y1, and the contiguous block m1u..s2 (encoded -inf == 0u), and out
  hipMemsetAsync(y1, 0, (size_t)N * 128 * sizeof(float), stream);
  hipMemsetAsync(m1u, 0, (size_t)N * 22 * sizeof(float), stream);
  hipMemsetAsync(out, 0, (size_t)out_size * sizeof(float), stream);

  // layer 1
  k_gemm1_att<<<(N + 31) / 32, 256, 0, stream>>>(x, W1, ats1, atd1, h1, as1, ad1, N);
  k_edge1_max<<<(E2 + 255) / 256, 256, 0, stream>>>(ei, E, N, as1, ad1, m1u);
  k_edge1_sum<<<(E2 + 255) / 256, 256, 0, stream>>>(ei, E, N, as1, ad1, m1u, s1);
  k_agg1<<<(E2 + 3) / 4, 256, 0, stream>>>(ei, E, N, as1, ad1, m1u, s1, h1, y1);

  // layer 2
  k_l2prep<<<(N + 3) / 4, 256, 0, stream>>>(y1, b1, W2, ats2, atd2, h2, as2, ad2, N);
  k_edge2_max<<<(E2 + 255) / 256, 256, 0, stream>>>(ei, E, N, as2, ad2, m2u);
  k_edge2_sum<<<(E2 + 255) / 256, 256, 0, stream>>>(ei, E, N, as2, ad2, m2u, s2);
  k_agg2<<<(E2 + 255) / 256, 256, 0, stream>>>(ei, E, N, as2, ad2, m2u, s2, h2, out);
  k_bias2<<<(out_size + 255) / 256, 256, 0, stream>>>(out, b2, out_size);
}

// Round 2
// 316.436 us; speedup vs baseline: 3.9755x; 3.9755x over previous
//
#include <hip/hip_runtime.h>
#include <math.h>

#define NEG_SLOPE 0.2f

__device__ __forceinline__ float lrelu(float x) { return x > 0.f ? x : NEG_SLOPE * x; }

// ---------------- Kernel A: h1 = x @ W1 (fp32, LDS-tiled), fused per-head attention dots
__global__ __launch_bounds__(256) void k_gemm1_att(
    const float* __restrict__ x, const float* __restrict__ W1,
    const float* __restrict__ att_src, const float* __restrict__ att_dst,
    float* __restrict__ h1, float* __restrict__ as1, float* __restrict__ ad1,
    int N)
{
  __shared__ float Wls[128 * 128];
  __shared__ float xls[32][128];
  const int tid = threadIdx.x;
  const float4* __restrict__ W4 = (const float4*)W1;
  float4* Wls4 = (float4*)Wls;
#pragma unroll
  for (int i = 0; i < 16; ++i) Wls4[tid + i * 256] = W4[tid + i * 256];

  const int cg = tid & 31;
  const int col = cg << 2;
  const int ng = tid >> 5;
  const int nb = ng << 2;
  const int n0 = blockIdx.x * 32;

  const float4 avs = *(const float4*)(att_src + col);
  const float4 avd = *(const float4*)(att_dst + col);

  const float4* __restrict__ x4 = (const float4*)x;
  float4* xls4 = (float4*)xls;
#pragma unroll
  for (int i = 0; i < 4; ++i) {
    int idx = tid + i * 256;
    int r = idx >> 5, c = idx & 31;
    int n = n0 + r; if (n >= N) n = N - 1;
    xls4[idx] = x4[(size_t)n * 32 + c];
  }
  __syncthreads();

  float4 a0 = {0,0,0,0}, a1 = {0,0,0,0}, a2 = {0,0,0,0}, a3 = {0,0,0,0};
#pragma unroll 8
  for (int k = 0; k < 128; ++k) {
    float4 w = Wls4[(k << 5) + cg];
    float x0 = xls[nb + 0][k];
    float x1 = xls[nb + 1][k];
    float x2 = xls[nb + 2][k];
    float x3 = xls[nb + 3][k];
    a0.x = fmaf(x0, w.x, a0.x); a0.y = fmaf(x0, w.y, a0.y); a0.z = fmaf(x0, w.z, a0.z); a0.w = fmaf(x0, w.w, a0.w);
    a1.x = fmaf(x1, w.x, a1.x); a1.y = fmaf(x1, w.y, a1.y); a1.z = fmaf(x1, w.z, a1.z); a1.w = fmaf(x1, w.w, a1.w);
    a2.x = fmaf(x2, w.x, a2.x); a2.y = fmaf(x2, w.y, a2.y); a2.z = fmaf(x2, w.z, a2.z); a2.w = fmaf(x2, w.w, a2.w);
    a3.x = fmaf(x3, w.x, a3.x); a3.y = fmaf(x3, w.y, a3.y); a3.z = fmaf(x3, w.z, a3.z); a3.w = fmaf(x3, w.w, a3.w);
  }

#define OUTJ(j, acc) { \
    int n = n0 + nb + j; \
    if (n < N) *(float4*)(h1 + (size_t)n * 128 + col) = acc; \
    float psv = acc.x*avs.x + acc.y*avs.y + acc.z*avs.z + acc.w*avs.w; \
    float pdv = acc.x*avd.x + acc.y*avd.y + acc.z*avd.z + acc.w*avd.w; \
    psv += __shfl_xor(psv, 1); psv += __shfl_xor(psv, 2); \
    pdv += __shfl_xor(pdv, 1); pdv += __shfl_xor(pdv, 2); \
    if ((tid & 3) == 0 && n < N) { as1[(size_t)n * 8 + (cg >> 2)] = psv; ad1[(size_t)n * 8 + (cg >> 2)] = pdv; } \
  }
  OUTJ(0, a0) OUTJ(1, a1) OUTJ(2, a2) OUTJ(3, a3)
#undef OUTJ
}

// ---------------- CSR build: histogram, 2-level exclusive scan, scatter
__global__ __launch_bounds__(256) void k_hist(const int* __restrict__ ei, int E, int N,
                                              int* __restrict__ deg) {
  int e = blockIdx.x * 256 + threadIdx.x;
  if (e >= E + N) return;
  int d = (e < E) ? ei[E + e] : e - E;
  atomicAdd(&deg[d], 1);
}

__global__ __launch_bounds__(256) void k_scan1(const int* __restrict__ deg,
                                               int* __restrict__ rowptr,
                                               int* __restrict__ bsum, int N) {
  __shared__ int sc[256];
  int b = blockIdx.x, t = threadIdx.x;
  int i0 = b * 512 + 2 * t, i1 = i0 + 1;
  int a = (i0 < N) ? deg[i0] : 0;
  int bb = (i1 < N) ? deg[i1] : 0;
  int s = a + bb;
  sc[t] = s; __syncthreads();
  int run = s;
  for (int dd = 1; dd < 256; dd <<= 1) {
    int v = (t >= dd) ? sc[t - dd] : 0; __syncthreads();
    run += v; sc[t] = run; __syncthreads();
  }
  int excl = run - s;
  if (i0 < N) rowptr[i0] = excl;
  if (i1 < N) rowptr[i1] = excl + a;
  if (t == 255) bsum[b] = run;
}

__global__ __launch_bounds__(256) void k_scan2(int* __restrict__ bsum, int nb) {
  __shared__ int sc[256];
  int t = threadIdx.x;
  int s = (t < nb) ? bsum[t] : 0;
  sc[t] = s; __syncthreads();
  int run = s;
  for (int dd = 1; dd < 256; dd <<= 1) {
    int v = (t >= dd) ? sc[t - dd] : 0; __syncthreads();
    run += v; sc[t] = run; __syncthreads();
  }
  if (t < nb) bsum[t] = run - s;
}

__global__ __launch_bounds__(256) void k_scan3(int* __restrict__ rowptr,
                                               const int* __restrict__ bsum,
                                               int* __restrict__ cursor, int N) {
  int i = blockIdx.x * 256 + threadIdx.x;
  if (i >= N) return;
  int v = rowptr[i] + bsum[i >> 9];
  rowptr[i] = v;
  cursor[i] = v;
}

__global__ __launch_bounds__(256) void k_scatter(const int* __restrict__ ei, int E, int N,
                                                 int* __restrict__ cursor,
                                                 int* __restrict__ srt) {
  int e = blockIdx.x * 256 + threadIdx.x;
  if (e >= E + N) return;
  int s, d;
  if (e < E) { s = ei[e]; d = ei[E + e]; } else { s = d = e - E; }
  int pos = atomicAdd(&cursor[d], 1);
  srt[pos] = s;
}

// ---------------- Fused layer-1: per-dst softmax (max+sum) + aggregation + ELU + GEMM2 + l2 att dots
// one 64-lane wave per dst node
__global__ __launch_bounds__(256) void k_agg1f(
    const int* __restrict__ rowptr, const int* __restrict__ deg, const int* __restrict__ srt,
    const float* __restrict__ as1, const float* __restrict__ ad1, const float* __restrict__ h1,
    const float* __restrict__ b1, const float* __restrict__ W2,
    const float* __restrict__ ats2, const float* __restrict__ atd2,
    float* __restrict__ h2, float* __restrict__ as2, float* __restrict__ ad2, int N)
{
  const int lane = threadIdx.x & 63;
  const int d = blockIdx.x * 4 + (threadIdx.x >> 6);
  if (d >= N) return;
  const int start = rowptr[d];
  const int dg = deg[d];

  const int h8 = lane & 7;      // head for phase 1
  const int slot = lane >> 3;   // 8 parallel edge slots
  const float adv = ad1[(size_t)d * 8 + h8];

  // phase 1a: per-head max over incoming edges
  float vmax = -1e30f;
  for (int c = slot; c < dg; c += 8) {
    int s = srt[start + c];
    vmax = fmaxf(vmax, lrelu(as1[(size_t)s * 8 + h8] + adv));
  }
  vmax = fmaxf(vmax, __shfl_xor(vmax, 8));
  vmax = fmaxf(vmax, __shfl_xor(vmax, 16));
  vmax = fmaxf(vmax, __shfl_xor(vmax, 32));

  // phase 1b: per-head exp-sum
  float ssum = 0.f;
  for (int c = slot; c < dg; c += 8) {
    int s = srt[start + c];
    ssum += expf(lrelu(as1[(size_t)s * 8 + h8] + adv) - vmax);
  }
  ssum += __shfl_xor(ssum, 8);
  ssum += __shfl_xor(ssum, 16);
  ssum += __shfl_xor(ssum, 32);

  // redistribute per-head stats: lane owns channels (2*lane, 2*lane+1) -> head = lane>>3
  const int hh = lane >> 3;
  const float m   = __shfl(vmax, hh);
  const float sm  = __shfl(ssum, hh);
  const float adh = __shfl(adv, hh);
  const float inv = 1.f / (sm + 1e-16f);

  // phase 2: aggregate alpha * h1[src]
  float2 acc = {0.f, 0.f};
  for (int c = 0; c < dg; ++c) {
    int s = srt[start + c];
    float alpha = expf(lrelu(as1[(size_t)s * 8 + hh] + adh) - m) * inv;
    float2 hv = *(const float2*)(h1 + (size_t)s * 128 + 2 * lane);
    acc.x = fmaf(alpha, hv.x, acc.x);
    acc.y = fmaf(alpha, hv.y, acc.y);
  }

  // epilogue: + b1, ELU, GEMM2 (128->2 wave reduce), layer-2 attention dots
  float2 bv = ((const float2*)b1)[lane];
  float v0 = acc.x + bv.x, v1 = acc.y + bv.y;
  v0 = v0 > 0.f ? v0 : expm1f(v0);
  v1 = v1 > 0.f ? v1 : expm1f(v1);
  float4 w = *(const float4*)(W2 + 4 * lane);  // W2[c0][0..1], W2[c1][0..1]
  float p0 = v0 * w.x + v1 * w.z;
  float p1 = v0 * w.y + v1 * w.w;
#pragma unroll
  for (int msk = 1; msk < 64; msk <<= 1) { p0 += __shfl_xor(p0, msk); p1 += __shfl_xor(p1, msk); }
  if (lane == 0) {
    h2[(size_t)d * 2]     = p0;
    h2[(size_t)d * 2 + 1] = p1;
    as2[d] = p0 * ats2[0] + p1 * ats2[1];
    ad2[d] = p0 * atd2[0] + p1 * atd2[1];
  }
}

// ---------------- Fused layer-2: 16 lanes per dst node (max, sum+aggregate, bias)
__global__ __launch_bounds__(256) void k_agg2f(
    const int* __restrict__ rowptr, const int* __restrict__ deg, const int* __restrict__ srt,
    const float* __restrict__ as2, const float* __restrict__ ad2, const float* __restrict__ h2,
    const float* __restrict__ b2, float* __restrict__ out, int N)
{
  const int l16 = threadIdx.x & 15;
  const int d = blockIdx.x * 16 + (threadIdx.x >> 4);
  if (d >= N) return;
  const int start = rowptr[d];
  const int dg = deg[d];
  const float ad = ad2[d];

  float vmax = -1e30f;
  for (int c = l16; c < dg; c += 16) {
    int s = srt[start + c];
    vmax = fmaxf(vmax, lrelu(as2[s] + ad));
  }
#pragma unroll
  for (int m = 1; m < 16; m <<= 1) vmax = fmaxf(vmax, __shfl_xor(vmax, m, 16));

  float se = 0.f, a0 = 0.f, a1 = 0.f;
  for (int c = l16; c < dg; c += 16) {
    int s = srt[start + c];
    float ex = expf(lrelu(as2[s] + ad) - vmax);
    float2 hv = *(const float2*)(h2 + (size_t)s * 2);
    se += ex;
    a0 = fmaf(ex, hv.x, a0);
    a1 = fmaf(ex, hv.y, a1);
  }
#pragma unroll
  for (int m = 1; m < 16; m <<= 1) {
    se += __shfl_xor(se, m, 16);
    a0 += __shfl_xor(a0, m, 16);
    a1 += __shfl_xor(a1, m, 16);
  }
  if (l16 == 0) {
    float inv = 1.f / (se + 1e-16f);
    out[(size_t)d * 2]     = a0 * inv + b2[0];
    out[(size_t)d * 2 + 1] = a1 * inv + b2[1];
  }
}

extern "C" void kernel_launch(void* const* d_in, const int* in_sizes, int n_in,
                              void* d_out, int out_size, void* d_ws, size_t ws_size,
                              hipStream_t stream) {
  const float* x    = (const float*)d_in[0];
  const int*   ei   = (const int*)d_in[1];
  const float* W1   = (const float*)d_in[2];
  const float* ats1 = (const float*)d_in[3];
  const float* atd1 = (const float*)d_in[4];
  const float* b1   = (const float*)d_in[5];
  const float* W2   = (const float*)d_in[6];
  const float* ats2 = (const float*)d_in[7];
  const float* atd2 = (const float*)d_in[8];
  const float* b2   = (const float*)d_in[9];
  float* out = (float*)d_out;

  const int N  = in_sizes[0] / 128;
  const int E  = in_sizes[1] / 2;
  const int E2 = E + N;
  const int nb = (N + 511) / 512;

  // workspace layout
  float* ws = (float*)d_ws;
  size_t off = 0;
  float* h1  = ws + off; off += (size_t)N * 128;
  float* as1 = ws + off; off += (size_t)N * 8;
  float* ad1 = ws + off; off += (size_t)N * 8;
  float* h2  = ws + off; off += (size_t)N * 2;
  float* as2 = ws + off; off += (size_t)N;
  float* ad2 = ws + off; off += (size_t)N;
  int* deg    = (int*)(ws + off); off += (size_t)N;
  int* rowptr = (int*)(ws + off); off += (size_t)N;
  int* cursor = (int*)(ws + off); off += (size_t)N;
  int* bsum   = (int*)(ws + off); off += 256;
  int* srt    = (int*)(ws + off); off += (size_t)E2;

  hipMemsetAsync(deg, 0, (size_t)N * sizeof(int), stream);

  // CSR build (shared by both layers)
  k_hist<<<(E2 + 255) / 256, 256, 0, stream>>>(ei, E, N, deg);
  k_scan1<<<nb, 256, 0, stream>>>(deg, rowptr, bsum, N);
  k_scan2<<<1, 256, 0, stream>>>(bsum, nb);
  k_scan3<<<(N + 255) / 256, 256, 0, stream>>>(rowptr, bsum, cursor, N);
  k_scatter<<<(E2 + 255) / 256, 256, 0, stream>>>(ei, E, N, cursor, srt);

  // layer 1 GEMM + attention dots
  k_gemm1_att<<<(N + 31) / 32, 256, 0, stream>>>(x, W1, ats1, atd1, h1, as1, ad1, N);

  // fused layer-1 softmax+aggregate+ELU+GEMM2+att dots
  k_agg1f<<<(N + 3) / 4, 256, 0, stream>>>(rowptr, deg, srt, as1, ad1, h1,
                                           b1, W2, ats2, atd2, h2, as2, ad2, N);

  // fused layer-2
  k_agg2f<<<(N + 15) / 16, 256, 0, stream>>>(rowptr, deg, srt, as2, ad2, h2, b2, out, N);
}

// Round 3
// 238.067 us; speedup vs baseline: 5.2842x; 1.3292x over previous
//
#include <hip/hip_runtime.h>
#include <hip/hip_bf16.h>
#include <math.h>

#define NEG_SLOPE 0.2f

typedef short bf16x8 __attribute__((ext_vector_type(8)));
typedef float f32x4 __attribute__((ext_vector_type(4)));

__device__ __forceinline__ float lrelu(float x) { return fmaxf(x, NEG_SLOPE * x); }

__device__ __forceinline__ ushort f2bf(float f) {
  __hip_bfloat16 b = __float2bfloat16(f);
  return *reinterpret_cast<ushort*>(&b);
}
__device__ __forceinline__ float bf2f_lo(unsigned u) { return __uint_as_float(u << 16); }
__device__ __forceinline__ float bf2f_hi(unsigned u) { return __uint_as_float(u & 0xffff0000u); }

// ---------------- W1 fp32 -> bf16, transposed [n][k] with XOR swizzle, into global scratch
__global__ __launch_bounds__(256) void k_prepW(const float* __restrict__ W1,
                                               ushort* __restrict__ Wg) {
  int t = blockIdx.x * 256 + threadIdx.x;
  if (t < 128 * 128) {
    int k = t >> 7, n = t & 127;
    Wg[n * 128 + (k ^ ((n & 7) << 3))] = f2bf(W1[t]);
  }
}

// ---------------- h1 = x @ W1 via bf16 MFMA. 64 nodes/block, 4 waves (16 rows each).
// A-frags straight from global x (fp32->bf16 in reg); B from swizzled LDS copy of Wg.
__global__ __launch_bounds__(256) void k_gemm1m(
    const float* __restrict__ x, const ushort* __restrict__ Wg,
    ushort* __restrict__ h1b, int N)
{
  __shared__ ushort Wls[128 * 128];
  const int tid = threadIdx.x;
  const float4* Wg4 = (const float4*)Wg;
  float4* Wl4 = (float4*)Wls;
#pragma unroll
  for (int i = 0; i < 8; ++i) Wl4[tid + i * 256] = Wg4[tid + i * 256];
  __syncthreads();

  const int lane = tid & 63, wid = tid >> 6;
  const int r0 = blockIdx.x * 64 + wid * 16;
  const int lr = lane & 15, kg = lane >> 4;   // kg = k-group 0..3
  int row = r0 + lr; if (row >= N) row = N - 1;
  const float* xr = x + (size_t)row * 128;

  f32x4 acc[8];
#pragma unroll
  for (int i = 0; i < 8; ++i) acc[i] = (f32x4){0.f, 0.f, 0.f, 0.f};

#pragma unroll
  for (int ks = 0; ks < 4; ++ks) {
    int k0 = ks * 32 + kg * 8;
    float4 xa = *(const float4*)(xr + k0);
    float4 xb = *(const float4*)(xr + k0 + 4);
    bf16x8 af;
    af[0] = f2bf(xa.x); af[1] = f2bf(xa.y); af[2] = f2bf(xa.z); af[3] = f2bf(xa.w);
    af[4] = f2bf(xb.x); af[5] = f2bf(xb.y); af[6] = f2bf(xb.z); af[7] = f2bf(xb.w);
#pragma unroll
    for (int nt = 0; nt < 8; ++nt) {
      int n = nt * 16 + lr;
      bf16x8 bfr = *(const bf16x8*)(Wls + n * 128 + (k0 ^ ((n & 7) << 3)));
      acc[nt] = __builtin_amdgcn_mfma_f32_16x16x32_bf16(af, bfr, acc[nt], 0, 0, 0);
    }
  }
  // C layout: col = lane&15, row = (lane>>4)*4 + reg
#pragma unroll
  for (int nt = 0; nt < 8; ++nt) {
#pragma unroll
    for (int i = 0; i < 4; ++i) {
      int r = r0 + kg * 4 + i;
      if (r < N) h1b[(size_t)r * 128 + nt * 16 + lr] = f2bf(acc[nt][i]);
    }
  }
}

// ---------------- attention dots from bf16 h1: as1/ad1 [N][8]
__global__ __launch_bounds__(256) void k_att1(
    const ushort* __restrict__ h1b, const float* __restrict__ ats1, const float* __restrict__ atd1,
    float* __restrict__ as1, float* __restrict__ ad1, int N)
{
  const int lane = threadIdx.x & 63;
  const int n = blockIdx.x * 4 + (threadIdx.x >> 6);
  if (n >= N) return;
  unsigned u = *(const unsigned*)(h1b + (size_t)n * 128 + 2 * lane);
  float hlo = bf2f_lo(u), hhi = bf2f_hi(u);
  float2 s = ((const float2*)ats1)[lane];
  float2 dd = ((const float2*)atd1)[lane];
  float ps = hlo * s.x + hhi * s.y;
  float pd = hlo * dd.x + hhi * dd.y;
  ps += __shfl_xor(ps, 1); ps += __shfl_xor(ps, 2); ps += __shfl_xor(ps, 4);
  pd += __shfl_xor(pd, 1); pd += __shfl_xor(pd, 2); pd += __shfl_xor(pd, 4);
  if ((lane & 7) == 0) {
    as1[(size_t)n * 8 + (lane >> 3)] = ps;
    ad1[(size_t)n * 8 + (lane >> 3)] = pd;
  }
}

// ---------------- CSR build: histogram, 2-level exclusive scan, scatter
__global__ __launch_bounds__(256) void k_hist(const int* __restrict__ ei, int E, int N,
                                              int* __restrict__ deg) {
  int e = blockIdx.x * 256 + threadIdx.x;
  if (e >= E + N) return;
  int d = (e < E) ? ei[E + e] : e - E;
  atomicAdd(&deg[d], 1);
}

__global__ __launch_bounds__(256) void k_scan1(const int* __restrict__ deg,
                                               int* __restrict__ rowptr,
                                               int* __restrict__ bsum, int N) {
  __shared__ int sc[256];
  int b = blockIdx.x, t = threadIdx.x;
  int i0 = b * 512 + 2 * t, i1 = i0 + 1;
  int a = (i0 < N) ? deg[i0] : 0;
  int bb = (i1 < N) ? deg[i1] : 0;
  int s = a + bb;
  sc[t] = s; __syncthreads();
  int run = s;
  for (int dd = 1; dd < 256; dd <<= 1) {
    int v = (t >= dd) ? sc[t - dd] : 0; __syncthreads();
    run += v; sc[t] = run; __syncthreads();
  }
  int excl = run - s;
  if (i0 < N) rowptr[i0] = excl;
  if (i1 < N) rowptr[i1] = excl + a;
  if (t == 255) bsum[b] = run;
}

__global__ __launch_bounds__(256) void k_scan2(int* __restrict__ bsum, int nb) {
  __shared__ int sc[256];
  int t = threadIdx.x;
  int s = (t < nb) ? bsum[t] : 0;
  sc[t] = s; __syncthreads();
  int run = s;
  for (int dd = 1; dd < 256; dd <<= 1) {
    int v = (t >= dd) ? sc[t - dd] : 0; __syncthreads();
    run += v; sc[t] = run; __syncthreads();
  }
  if (t < nb) bsum[t] = run - s;
}

__global__ __launch_bounds__(256) void k_scan3(int* __restrict__ rowptr,
                                               const int* __restrict__ bsum,
                                               int* __restrict__ cursor, int N) {
  int i = blockIdx.x * 256 + threadIdx.x;
  if (i >= N) return;
  int v = rowptr[i] + bsum[i >> 9];
  rowptr[i] = v;
  cursor[i] = v;
}

__global__ __launch_bounds__(256) void k_scatter(const int* __restrict__ ei, int E, int N,
                                                 int* __restrict__ cursor,
                                                 int* __restrict__ srt) {
  int e = blockIdx.x * 256 + threadIdx.x;
  if (e >= E + N) return;
  int s, d;
  if (e < E) { s = ei[e]; d = ei[E + e]; } else { s = d = e - E; }
  int pos = atomicAdd(&cursor[d], 1);
  srt[pos] = s;
}

// ---------------- Fused layer-1: softmax (no max shift) + aggregate + ELU + GEMM2 + l2 dots
// one 64-lane wave per dst; phase 2 does 2 edges/iter (32 lanes x 4 ch each)
__global__ __launch_bounds__(256) void k_agg1f(
    const int* __restrict__ rowptr, const int* __restrict__ deg, const int* __restrict__ srt,
    const float* __restrict__ as1, const float* __restrict__ ad1, const ushort* __restrict__ h1b,
    const float* __restrict__ b1, const float* __restrict__ W2,
    const float* __restrict__ ats2, const float* __restrict__ atd2,
    float* __restrict__ h2, float* __restrict__ as2, float* __restrict__ ad2, int N)
{
  const int lane = threadIdx.x & 63;
  const int d = blockIdx.x * 4 + (threadIdx.x >> 6);
  if (d >= N) return;
  const int start = rowptr[d];
  const int dg = deg[d];

  // phase 1: per-head exp-sum (8 slots x 8 heads)
  const int h8 = lane & 7, slot = lane >> 3;
  const float adv = ad1[(size_t)d * 8 + h8];
  float ssum = 0.f;
  for (int c = slot; c < dg; c += 8) {
    int s = srt[start + c];
    ssum += __expf(lrelu(as1[(size_t)s * 8 + h8] + adv));
  }
  ssum += __shfl_xor(ssum, 8);
  ssum += __shfl_xor(ssum, 16);
  ssum += __shfl_xor(ssum, 32);

  // phase 2: lane covers channels 4*l32..+3 (head hh), halves cover alternating edges
  const int l32 = lane & 31, half = lane >> 5;
  const int hh = l32 >> 2;
  const float adh = __shfl(adv, hh);
  const float inv = 1.f / (__shfl(ssum, hh) + 1e-16f);

  f32x4 acc = (f32x4){0.f, 0.f, 0.f, 0.f};
  for (int c = 0; c < dg; c += 2) {
    int cc = c + half;
    int s = srt[start + (cc < dg ? cc : dg - 1)];
    float e = lrelu(as1[(size_t)s * 8 + hh] + adh);
    float au = (cc < dg) ? __expf(e) : 0.f;
    uint2 hv = *(const uint2*)(h1b + (size_t)s * 128 + 4 * l32);
    acc[0] = fmaf(au, bf2f_lo(hv.x), acc[0]);
    acc[1] = fmaf(au, bf2f_hi(hv.x), acc[1]);
    acc[2] = fmaf(au, bf2f_lo(hv.y), acc[2]);
    acc[3] = fmaf(au, bf2f_hi(hv.y), acc[3]);
  }
#pragma unroll
  for (int i = 0; i < 4; ++i) acc[i] += __shfl_xor(acc[i], 32);

  // epilogue: normalize, +b1, ELU, GEMM2 (128->2), layer-2 attention dots
  float4 bv = ((const float4*)b1)[l32];
  float v0 = acc[0] * inv + bv.x;
  float v1 = acc[1] * inv + bv.y;
  float v2 = acc[2] * inv + bv.z;
  float v3 = acc[3] * inv + bv.w;
  v0 = v0 > 0.f ? v0 : expm1f(v0);
  v1 = v1 > 0.f ? v1 : expm1f(v1);
  v2 = v2 > 0.f ? v2 : expm1f(v2);
  v3 = v3 > 0.f ? v3 : expm1f(v3);
  float4 wA = *(const float4*)(W2 + 8 * l32);       // rows 4*l32, 4*l32+1
  float4 wB = *(const float4*)(W2 + 8 * l32 + 4);   // rows 4*l32+2, 4*l32+3
  float p0 = v0 * wA.x + v1 * wA.z + v2 * wB.x + v3 * wB.z;
  float p1 = v0 * wA.y + v1 * wA.w + v2 * wB.y + v3 * wB.w;
#pragma unroll
  for (int m = 1; m < 32; m <<= 1) { p0 += __shfl_xor(p0, m); p1 += __shfl_xor(p1, m); }
  if (lane == 0) {
    h2[(size_t)d * 2]     = p0;
    h2[(size_t)d * 2 + 1] = p1;
    as2[d] = p0 * ats2[0] + p1 * ats2[1];
    ad2[d] = p0 * atd2[0] + p1 * atd2[1];
  }
}

// ---------------- Fused layer-2: 16 lanes per dst (single pass, no max shift)
__global__ __launch_bounds__(256) void k_agg2f(
    const int* __restrict__ rowptr, const int* __restrict__ deg, const int* __restrict__ srt,
    const float* __restrict__ as2, const float* __restrict__ ad2, const float* __restrict__ h2,
    const float* __restrict__ b2, float* __restrict__ out, int N)
{
  const int l16 = threadIdx.x & 15;
  const int d = blockIdx.x * 16 + (threadIdx.x >> 4);
  if (d >= N) return;
  const int start = rowptr[d];
  const int dg = deg[d];
  const float ad = ad2[d];

  float se = 0.f, a0 = 0.f, a1 = 0.f;
  for (int c = l16; c < dg; c += 16) {
    int s = srt[start + c];
    float ex = __expf(lrelu(as2[s] + ad));
    float2 hv = *(const float2*)(h2 + (size_t)s * 2);
    se += ex;
    a0 = fmaf(ex, hv.x, a0);
    a1 = fmaf(ex, hv.y, a1);
  }
#pragma unroll
  for (int m = 1; m < 16; m <<= 1) {
    se += __shfl_xor(se, m, 16);
    a0 += __shfl_xor(a0, m, 16);
    a1 += __shfl_xor(a1, m, 16);
  }
  if (l16 == 0) {
    float invs = 1.f / (se + 1e-16f);
    out[(size_t)d * 2]     = a0 * invs + b2[0];
    out[(size_t)d * 2 + 1] = a1 * invs + b2[1];
  }
}

extern "C" void kernel_launch(void* const* d_in, const int* in_sizes, int n_in,
                              void* d_out, int out_size, void* d_ws, size_t ws_size,
                              hipStream_t stream) {
  const float* x    = (const float*)d_in[0];
  const int*   ei   = (const int*)d_in[1];
  const float* W1   = (const float*)d_in[2];
  const float* ats1 = (const float*)d_in[3];
  const float* atd1 = (const float*)d_in[4];
  const float* b1   = (const float*)d_in[5];
  const float* W2   = (const float*)d_in[6];
  const float* ats2 = (const float*)d_in[7];
  const float* atd2 = (const float*)d_in[8];
  const float* b2   = (const float*)d_in[9];
  float* out = (float*)d_out;

  const int N  = in_sizes[0] / 128;
  const int E  = in_sizes[1] / 2;
  const int E2 = E + N;
  const int nb = (N + 511) / 512;

  // workspace layout
  float* ws = (float*)d_ws;
  size_t off = 0;
  ushort* h1b = (ushort*)(ws + off); off += (size_t)N * 64;   // N*128 bf16
  float* as1 = ws + off; off += (size_t)N * 8;
  float* ad1 = ws + off; off += (size_t)N * 8;
  float* h2  = ws + off; off += (size_t)N * 2;
  float* as2 = ws + off; off += (size_t)N;
  float* ad2 = ws + off; off += (size_t)N;
  int* deg    = (int*)(ws + off); off += (size_t)N;
  int* rowptr = (int*)(ws + off); off += (size_t)N;
  int* cursor = (int*)(ws + off); off += (size_t)N;
  int* bsum   = (int*)(ws + off); off += 256;
  int* srt    = (int*)(ws + off); off += (size_t)E2;
  ushort* Wg  = (ushort*)(ws + off); off += 128 * 64;         // 128*128 bf16

  hipMemsetAsync(deg, 0, (size_t)N * sizeof(int), stream);

  // CSR build (shared by both layers)
  k_hist<<<(E2 + 255) / 256, 256, 0, stream>>>(ei, E, N, deg);
  k_scan1<<<nb, 256, 0, stream>>>(deg, rowptr, bsum, N);
  k_scan2<<<1, 256, 0, stream>>>(bsum, nb);
  k_scan3<<<(N + 255) / 256, 256, 0, stream>>>(rowptr, bsum, cursor, N);
  k_scatter<<<(E2 + 255) / 256, 256, 0, stream>>>(ei, E, N, cursor, srt);

  // layer 1 GEMM (bf16 MFMA) + attention dots
  k_prepW<<<64, 256, 0, stream>>>(W1, Wg);
  k_gemm1m<<<(N + 63) / 64, 256, 0, stream>>>(x, Wg, h1b, N);
  k_att1<<<(N + 3) / 4, 256, 0, stream>>>(h1b, ats1, atd1, as1, ad1, N);

  // fused layer-1 softmax+aggregate+ELU+GEMM2+att dots
  k_agg1f<<<(N + 3) / 4, 256, 0, stream>>>(rowptr, deg, srt, as1, ad1, h1b,
                                           b1, W2, ats2, atd2, h2, as2, ad2, N);

  // fused layer-2
  k_agg2f<<<(N + 15) / 16, 256, 0, stream>>>(rowptr, deg, srt, as2, ad2, h2, b2, out, N);
}

// Round 4
// 195.511 us; speedup vs baseline: 6.4344x; 1.2177x over previous
//
#include <hip/hip_runtime.h>
#include <hip/hip_bf16.h>
#include <math.h>

#define NEG_SLOPE 0.2f

typedef short bf16x8 __attribute__((ext_vector_type(8)));
typedef float f32x4 __attribute__((ext_vector_type(4)));

__device__ __forceinline__ float lrelu(float x) { return fmaxf(x, NEG_SLOPE * x); }

__device__ __forceinline__ ushort f2bf(float f) {
  __hip_bfloat16 b = __float2bfloat16(f);
  return *reinterpret_cast<ushort*>(&b);
}
__device__ __forceinline__ float bf2f_lo(unsigned u) { return __uint_as_float(u << 16); }
__device__ __forceinline__ float bf2f_hi(unsigned u) { return __uint_as_float(u & 0xffff0000u); }

// ---------------- prep: Wg[144 cols][128 k] bf16, XOR-swizzled.
// cols 0..127 = W1^T ; cols 128..135 = u_src[k][head] ; 136..143 = u_dst[k][head]
// where u[k][h] = sum_ch W1[k][h*16+ch] * att[h][ch]  (so  x @ u = h . att)
__global__ __launch_bounds__(256) void k_prep(
    const float* __restrict__ W1, const float* __restrict__ ats1, const float* __restrict__ atd1,
    ushort* __restrict__ Wg)
{
  int t = blockIdx.x * 256 + threadIdx.x;
  if (t < 128 * 128) {
    int k = t >> 7, n = t & 127;
    Wg[(size_t)n * 128 + (k ^ ((n & 7) << 3))] = f2bf(W1[t]);
  } else if (t < 128 * 128 + 128 * 16) {
    int tt = t - 128 * 128;
    int k = tt >> 4;          // 0..127
    int c = tt & 15;          // 0..7 -> as, 8..15 -> ad
    int head = c & 7;
    const float* av = (c < 8) ? ats1 : atd1;
    float s = 0.f;
#pragma unroll
    for (int ch = 0; ch < 16; ++ch)
      s += W1[k * 128 + head * 16 + ch] * av[head * 16 + ch];
    int n = 128 + c;
    Wg[(size_t)n * 128 + (k ^ ((n & 7) << 3))] = f2bf(s);
  }
}

// ---------------- h1 = x @ W1 via bf16 MFMA, 64 nodes/block, 4 waves.
// 9 column tiles: 0..7 -> h1b (bf16), tile 8 -> as1/ad1 (fp32)
__global__ __launch_bounds__(256) void k_gemm1m(
    const float* __restrict__ x, const ushort* __restrict__ Wg,
    ushort* __restrict__ h1b, float* __restrict__ as1, float* __restrict__ ad1, int N)
{
  __shared__ ushort Wls[144 * 128];
  const int tid = threadIdx.x;
  const float4* Wg4 = (const float4*)Wg;
  float4* Wl4 = (float4*)Wls;
#pragma unroll
  for (int i = 0; i < 9; ++i) Wl4[tid + i * 256] = Wg4[tid + i * 256];
  __syncthreads();

  const int lane = tid & 63, wid = tid >> 6;
  const int r0 = blockIdx.x * 64 + wid * 16;
  const int lr = lane & 15, kg = lane >> 4;
  int row = r0 + lr; if (row >= N) row = N - 1;
  const float* xr = x + (size_t)row * 128;

  f32x4 acc[9];
#pragma unroll
  for (int i = 0; i < 9; ++i) acc[i] = (f32x4){0.f, 0.f, 0.f, 0.f};

#pragma unroll
  for (int ks = 0; ks < 4; ++ks) {
    int k0 = ks * 32 + kg * 8;
    float4 xa = *(const float4*)(xr + k0);
    float4 xb = *(const float4*)(xr + k0 + 4);
    bf16x8 af;
    af[0] = f2bf(xa.x); af[1] = f2bf(xa.y); af[2] = f2bf(xa.z); af[3] = f2bf(xa.w);
    af[4] = f2bf(xb.x); af[5] = f2bf(xb.y); af[6] = f2bf(xb.z); af[7] = f2bf(xb.w);
#pragma unroll
    for (int nt = 0; nt < 9; ++nt) {
      int n = nt * 16 + lr;
      bf16x8 bfr = *(const bf16x8*)(Wls + n * 128 + (k0 ^ ((n & 7) << 3)));
      acc[nt] = __builtin_amdgcn_mfma_f32_16x16x32_bf16(af, bfr, acc[nt], 0, 0, 0);
    }
  }
  // C layout: col = lane&15, row = (lane>>4)*4 + reg
#pragma unroll
  for (int nt = 0; nt < 8; ++nt) {
#pragma unroll
    for (int i = 0; i < 4; ++i) {
      int r = r0 + kg * 4 + i;
      if (r < N) h1b[(size_t)r * 128 + nt * 16 + lr] = f2bf(acc[nt][i]);
    }
  }
#pragma unroll
  for (int i = 0; i < 4; ++i) {
    int r = r0 + kg * 4 + i;
    if (r < N) {
      if (lr < 8) as1[(size_t)r * 8 + lr]     = acc[8][i];
      else        ad1[(size_t)r * 8 + lr - 8] = acc[8][i];
    }
  }
}

// ---------------- CSR build: histogram, 2-level exclusive scan, scatter
__global__ __launch_bounds__(256) void k_hist(const int* __restrict__ ei, int E, int N,
                                              int* __restrict__ deg) {
  int e = blockIdx.x * 256 + threadIdx.x;
  if (e >= E + N) return;
  int d = (e < E) ? ei[E + e] : e - E;
  atomicAdd(&deg[d], 1);
}

__global__ __launch_bounds__(256) void k_scan1(const int* __restrict__ deg,
                                               int* __restrict__ rowptr,
                                               int* __restrict__ bsum, int N) {
  __shared__ int sc[256];
  int b = blockIdx.x, t = threadIdx.x;
  int i0 = b * 512 + 2 * t, i1 = i0 + 1;
  int a = (i0 < N) ? deg[i0] : 0;
  int bb = (i1 < N) ? deg[i1] : 0;
  int s = a + bb;
  sc[t] = s; __syncthreads();
  int run = s;
  for (int dd = 1; dd < 256; dd <<= 1) {
    int v = (t >= dd) ? sc[t - dd] : 0; __syncthreads();
    run += v; sc[t] = run; __syncthreads();
  }
  int excl = run - s;
  if (i0 < N) rowptr[i0] = excl;
  if (i1 < N) rowptr[i1] = excl + a;
  if (t == 255) bsum[b] = run;
}

__global__ __launch_bounds__(256) void k_scan2(int* __restrict__ bsum, int nb) {
  __shared__ int sc[256];
  int t = threadIdx.x;
  int s = (t < nb) ? bsum[t] : 0;
  sc[t] = s; __syncthreads();
  int run = s;
  for (int dd = 1; dd < 256; dd <<= 1) {
    int v = (t >= dd) ? sc[t - dd] : 0; __syncthreads();
    run += v; sc[t] = run; __syncthreads();
  }
  if (t < nb) bsum[t] = run - s;
}

__global__ __launch_bounds__(256) void k_scan3(int* __restrict__ rowptr,
                                               const int* __restrict__ bsum,
                                               int* __restrict__ cursor, int N) {
  int i = blockIdx.x * 256 + threadIdx.x;
  if (i >= N) return;
  int v = rowptr[i] + bsum[i >> 9];
  rowptr[i] = v;
  cursor[i] = v;
}

__global__ __launch_bounds__(256) void k_scatter(const int* __restrict__ ei, int E, int N,
                                                 int* __restrict__ cursor,
                                                 int* __restrict__ srt) {
  int e = blockIdx.x * 256 + threadIdx.x;
  if (e >= E + N) return;
  int s, d;
  if (e < E) { s = ei[e]; d = ei[E + e]; } else { s = d = e - E; }
  int pos = atomicAdd(&cursor[d], 1);
  srt[pos] = s;
}

// ---------------- Fused layer-1: single-pass softmax+aggregate (+ELU+GEMM2+l2 dots)
// one wave per dst; 4 edge-groups x 16 lanes x 8 ch; normalize at the end
__global__ __launch_bounds__(256) void k_agg1f(
    const int* __restrict__ rowptr, const int* __restrict__ deg, const int* __restrict__ srt,
    const float* __restrict__ as1, const float* __restrict__ ad1, const ushort* __restrict__ h1b,
    const float* __restrict__ b1, const float* __restrict__ W2,
    const float* __restrict__ ats2, const float* __restrict__ atd2,
    float4* __restrict__ nd2, int N)
{
  const int lane = threadIdx.x & 63;
  const int d = blockIdx.x * 4 + (threadIdx.x >> 6);
  if (d >= N) return;
  const int start = rowptr[d];
  const int dg = deg[d];
  const int g = lane >> 4, l16 = lane & 15;
  const int hh = l16 >> 1;                     // head of this lane's 8 channels
  const float adh = ad1[(size_t)d * 8 + hh];

  f32x4 accA = (f32x4){0.f,0.f,0.f,0.f}, accB = (f32x4){0.f,0.f,0.f,0.f};
  float sumA = 0.f;
  int c = g;
  int s = (c < dg) ? srt[start + c] : 0;
  while (c < dg) {
    int c2 = c + 4;
    int s2 = (c2 < dg) ? srt[start + c2] : 0;   // prefetch next edge index
    float au = __expf(lrelu(as1[(size_t)s * 8 + hh] + adh));
    uint4 hv = *(const uint4*)(h1b + (size_t)s * 128 + 8 * l16);
    sumA += au;
    accA[0] = fmaf(au, bf2f_lo(hv.x), accA[0]);
    accA[1] = fmaf(au, bf2f_hi(hv.x), accA[1]);
    accA[2] = fmaf(au, bf2f_lo(hv.y), accA[2]);
    accA[3] = fmaf(au, bf2f_hi(hv.y), accA[3]);
    accB[0] = fmaf(au, bf2f_lo(hv.z), accB[0]);
    accB[1] = fmaf(au, bf2f_hi(hv.z), accB[1]);
    accB[2] = fmaf(au, bf2f_lo(hv.w), accB[2]);
    accB[3] = fmaf(au, bf2f_hi(hv.w), accB[3]);
    c = c2; s = s2;
  }
#pragma unroll
  for (int i = 0; i < 4; ++i) {
    accA[i] += __shfl_xor(accA[i], 16); accA[i] += __shfl_xor(accA[i], 32);
    accB[i] += __shfl_xor(accB[i], 16); accB[i] += __shfl_xor(accB[i], 32);
  }
  sumA += __shfl_xor(sumA, 16); sumA += __shfl_xor(sumA, 32);
  const float inv = 1.f / (sumA + 1e-16f);

  // epilogue: normalize, +b1, ELU, GEMM2 (128->2), layer-2 attention dots
  float4 b0 = *(const float4*)(b1 + 8 * l16);
  float4 b4 = *(const float4*)(b1 + 8 * l16 + 4);
  float v[8];
  v[0] = accA[0] * inv + b0.x; v[1] = accA[1] * inv + b0.y;
  v[2] = accA[2] * inv + b0.z; v[3] = accA[3] * inv + b0.w;
  v[4] = accB[0] * inv + b4.x; v[5] = accB[1] * inv + b4.y;
  v[6] = accB[2] * inv + b4.z; v[7] = accB[3] * inv + b4.w;
#pragma unroll
  for (int j = 0; j < 8; ++j) v[j] = v[j] > 0.f ? v[j] : expm1f(v[j]);
  const float4* W24 = (const float4*)(W2 + 16 * l16);
  float4 w0 = W24[0], w1 = W24[1], w2 = W24[2], w3 = W24[3];
  float p0 = v[0]*w0.x + v[1]*w0.z + v[2]*w1.x + v[3]*w1.z
           + v[4]*w2.x + v[5]*w2.z + v[6]*w3.x + v[7]*w3.z;
  float p1 = v[0]*w0.y + v[1]*w0.w + v[2]*w1.y + v[3]*w1.w
           + v[4]*w2.y + v[5]*w2.w + v[6]*w3.y + v[7]*w3.w;
#pragma unroll
  for (int m = 1; m < 16; m <<= 1) { p0 += __shfl_xor(p0, m); p1 += __shfl_xor(p1, m); }
  if (lane == 0) {
    float a2 = p0 * ats2[0] + p1 * ats2[1];
    float d2 = p0 * atd2[0] + p1 * atd2[1];
    nd2[d] = make_float4(p0, p1, a2, d2);
  }
}

// ---------------- Fused layer-2: 16 lanes per dst; one float4 load per edge
__global__ __launch_bounds__(256) void k_agg2f(
    const int* __restrict__ rowptr, const int* __restrict__ deg, const int* __restrict__ srt,
    const float4* __restrict__ nd2, const float* __restrict__ b2,
    float* __restrict__ out, int N)
{
  const int l16 = threadIdx.x & 15;
  const int d = blockIdx.x * 16 + (threadIdx.x >> 4);
  if (d >= N) return;
  const int start = rowptr[d];
  const int dg = deg[d];
  const float adv = nd2[d].w;

  float se = 0.f, a0 = 0.f, a1 = 0.f;
  for (int c = l16; c < dg; c += 16) {
    int s = srt[start + c];
    float4 r = nd2[s];
    float ex = __expf(lrelu(r.z + adv));
    se += ex;
    a0 = fmaf(ex, r.x, a0);
    a1 = fmaf(ex, r.y, a1);
  }
#pragma unroll
  for (int m = 1; m < 16; m <<= 1) {
    se += __shfl_xor(se, m, 16);
    a0 += __shfl_xor(a0, m, 16);
    a1 += __shfl_xor(a1, m, 16);
  }
  if (l16 == 0) {
    float invs = 1.f / (se + 1e-16f);
    out[(size_t)d * 2]     = a0 * invs + b2[0];
    out[(size_t)d * 2 + 1] = a1 * invs + b2[1];
  }
}

extern "C" void kernel_launch(void* const* d_in, const int* in_sizes, int n_in,
                              void* d_out, int out_size, void* d_ws, size_t ws_size,
                              hipStream_t stream) {
  const float* x    = (const float*)d_in[0];
  const int*   ei   = (const int*)d_in[1];
  const float* W1   = (const float*)d_in[2];
  const float* ats1 = (const float*)d_in[3];
  const float* atd1 = (const float*)d_in[4];
  const float* b1   = (const float*)d_in[5];
  const float* W2   = (const float*)d_in[6];
  const float* ats2 = (const float*)d_in[7];
  const float* atd2 = (const float*)d_in[8];
  const float* b2   = (const float*)d_in[9];
  float* out = (float*)d_out;

  const int N  = in_sizes[0] / 128;
  const int E  = in_sizes[1] / 2;
  const int E2 = E + N;
  const int nb = (N + 511) / 512;

  // workspace layout (floats)
  float* ws = (float*)d_ws;
  size_t off = 0;
  ushort* h1b = (ushort*)(ws + off); off += (size_t)N * 64;   // N*128 bf16
  float* as1 = ws + off; off += (size_t)N * 8;
  float* ad1 = ws + off; off += (size_t)N * 8;
  float4* nd2 = (float4*)(ws + off); off += (size_t)N * 4;
  int* deg    = (int*)(ws + off); off += (size_t)N;
  int* rowptr = (int*)(ws + off); off += (size_t)N;
  int* cursor = (int*)(ws + off); off += (size_t)N;
  int* bsum   = (int*)(ws + off); off += 256;
  int* srt    = (int*)(ws + off); off += (size_t)E2;
  ushort* Wg  = (ushort*)(ws + off); off += 144 * 64;         // 144*128 bf16

  hipMemsetAsync(deg, 0, (size_t)N * sizeof(int), stream);

  // CSR build (shared by both layers)
  k_hist<<<(E2 + 255) / 256, 256, 0, stream>>>(ei, E, N, deg);
  k_scan1<<<nb, 256, 0, stream>>>(deg, rowptr, bsum, N);
  k_scan2<<<1, 256, 0, stream>>>(bsum, nb);
  k_scan3<<<(N + 255) / 256, 256, 0, stream>>>(rowptr, bsum, cursor, N);
  k_scatter<<<(E2 + 255) / 256, 256, 0, stream>>>(ei, E, N, cursor, srt);

  // layer-1 GEMM (bf16 MFMA) with fused attention-dot columns
  k_prep<<<(128 * 128 + 128 * 16 + 255) / 256, 256, 0, stream>>>(W1, ats1, atd1, Wg);
  k_gemm1m<<<(N + 63) / 64, 256, 0, stream>>>(x, Wg, h1b, as1, ad1, N);

  // fused layer-1 softmax+aggregate+ELU+GEMM2+att dots
  k_agg1f<<<(N + 3) / 4, 256, 0, stream>>>(rowptr, deg, srt, as1, ad1, h1b,
                                           b1, W2, ats2, atd2, nd2, N);

  // fused layer-2
  k_agg2f<<<(N + 15) / 16, 256, 0, stream>>>(rowptr, deg, srt, nd2, b2, out, N);
}